// Round 1
// baseline (127.570 us; speedup 1.0000x reference)
//
#include <hip/hip_runtime.h>

#define DIM   1024
#define BATCH 8
#define QLEN  4096
#define SEQ   128
#define NMULT 2

// v[m*BATCH+b][d] = c_attn_b[m][DIM+d] + sum_e h_last[b][e] * c_attn_w[m][e][DIM+d]
__global__ void __launch_bounds__(256) kv_kernel(const float* __restrict__ hidden,
                                                 const float* __restrict__ c_attn_w,
                                                 const float* __restrict__ c_attn_b,
                                                 float* __restrict__ v) {
    int bid = blockIdx.x;                 // 64 blocks: m(2) * b(8) * dchunk(4)
    int m = bid >> 5;
    int b = (bid >> 2) & 7;
    int d = ((bid & 3) << 8) + threadIdx.x;
    const float* h = hidden + (size_t)b * (SEQ * DIM) + (size_t)(SEQ - 1) * DIM;
    const float* w = c_attn_w + (size_t)m * DIM * (2 * DIM) + DIM + d;
    float acc = c_attn_b[m * 2 * DIM + DIM + d];
#pragma unroll 8
    for (int e = 0; e < DIM; ++e) {
        acc += h[e] * w[(size_t)e * (2 * DIM)];
    }
    v[(m * BATCH + b) * DIM + d] = acc;
}

// y[m*BATCH+b][e] = c_proj_b[m][e] + sum_d v[m*BATCH+b][d] * c_proj_w[m][d][e]
__global__ void __launch_bounds__(256) proj_kernel(const float* __restrict__ v,
                                                   const float* __restrict__ c_proj_w,
                                                   const float* __restrict__ c_proj_b,
                                                   float* __restrict__ y) {
    int bid = blockIdx.x;                 // 64 blocks: m(2) * b(8) * echunk(4)
    int m = bid >> 5;
    int b = (bid >> 2) & 7;
    int e = ((bid & 3) << 8) + threadIdx.x;
    const float* vr = v + (m * BATCH + b) * DIM;
    const float* w = c_proj_w + (size_t)m * DIM * DIM + e;
    float acc = c_proj_b[m * DIM + e];
#pragma unroll 8
    for (int d = 0; d < DIM; ++d) {
        acc += vr[d] * w[(size_t)d * DIM];
    }
    y[(m * BATCH + b) * DIM + e] = acc;
}

// out[b,q,e] = y[0,b,e] + (b==0 ? y[1,0,e] : 0), broadcast over q
__global__ void __launch_bounds__(256) bcast_kernel(const float* __restrict__ y,
                                                    float* __restrict__ out) {
    const int total4 = BATCH * QLEN * (DIM / 4);   // 8,388,608 float4 stores
    const float4* y4 = reinterpret_cast<const float4*>(y);
    float4* o4 = reinterpret_cast<float4*>(out);
    int stride = gridDim.x * blockDim.x;
    for (int i = blockIdx.x * blockDim.x + threadIdx.x; i < total4; i += stride) {
        int e4 = i & (DIM / 4 - 1);
        int bq = i >> 8;                  // (b,q) combined
        int b = bq >> 12;                 // 4096 q per b
        float4 val = y4[b * (DIM / 4) + e4];            // y[0,b,:] rows
        if (b == 0) {
            float4 y1 = y4[BATCH * (DIM / 4) + e4];     // y[1,0,:]
            val.x += y1.x; val.y += y1.y; val.z += y1.z; val.w += y1.w;
        }
        o4[i] = val;
    }
}

extern "C" void kernel_launch(void* const* d_in, const int* in_sizes, int n_in,
                              void* d_out, int out_size, void* d_ws, size_t ws_size,
                              hipStream_t stream) {
    // input order: encoder_hidden_states, hidden_states, q_w, q_b,
    //              c_attn_w, c_attn_b, c_proj_w, c_proj_b
    const float* hidden   = (const float*)d_in[1];
    const float* c_attn_w = (const float*)d_in[4];
    const float* c_attn_b = (const float*)d_in[5];
    const float* c_proj_w = (const float*)d_in[6];
    const float* c_proj_b = (const float*)d_in[7];
    float* out = (float*)d_out;

    float* v = (float*)d_ws;                    // NMULT*BATCH*DIM f32 = 64 KB
    float* y = v + NMULT * BATCH * DIM;         // another 64 KB

    kv_kernel<<<64, 256, 0, stream>>>(hidden, c_attn_w, c_attn_b, v);
    proj_kernel<<<64, 256, 0, stream>>>(v, c_proj_w, c_proj_b, y);
    bcast_kernel<<<2048, 256, 0, stream>>>(y, out);
}

// Round 2
// 47.526 us; speedup vs baseline: 2.6842x; 2.6842x over previous
//
#include <hip/hip_runtime.h>

#define DIM    1024
#define BATCH  8
#define QLEN   4096
#define SEQ    128
#define NMULT  2
#define ESPLIT 16
#define ECHUNK (DIM / ESPLIT)   // 64

// v = c_attn_b[:, DIM:], y = c_proj_b  (re-initialized EVERY call; atomics below)
__global__ void __launch_bounds__(256) init_kernel(const float* __restrict__ c_attn_b,
                                                   const float* __restrict__ c_proj_b,
                                                   float* __restrict__ v,
                                                   float* __restrict__ y) {
    int idx = blockIdx.x * 256 + threadIdx.x;   // 32768 threads
    int half = idx & (NMULT * BATCH * DIM - 1); // 0..16383
    int m = half >> 13;
    int d = half & (DIM - 1);
    if (idx < NMULT * BATCH * DIM) {
        v[half] = c_attn_b[m * 2 * DIM + DIM + d];
    } else {
        y[half] = c_proj_b[m * DIM + d];
    }
}

// v[m,b,d] += sum_{e in chunk} h_last[b,e] * c_attn_w[m,e,DIM+d]
__global__ void __launch_bounds__(256) kv_split_kernel(const float* __restrict__ hidden,
                                                       const float* __restrict__ c_attn_w,
                                                       float* __restrict__ v) {
    int bid = blockIdx.x;            // 256 = m(2) * b(8) * chunk(16)
    int m = bid >> 7;
    int b = (bid >> 4) & 7;
    int c = bid & 15;
    int tid = threadIdx.x;           // owns d = 4*tid .. 4*tid+3
    const float* h = hidden + (size_t)b * (SEQ * DIM) + (size_t)(SEQ - 1) * DIM + c * ECHUNK;
    const float* w = c_attn_w + (size_t)m * DIM * (2 * DIM)
                   + (size_t)(c * ECHUNK) * (2 * DIM) + DIM + 4 * tid;
    float4 acc = make_float4(0.f, 0.f, 0.f, 0.f);
#pragma unroll 16
    for (int e = 0; e < ECHUNK; ++e) {
        float he = h[e];
        float4 w4 = *reinterpret_cast<const float4*>(w + (size_t)e * (2 * DIM));
        acc.x += he * w4.x; acc.y += he * w4.y; acc.z += he * w4.z; acc.w += he * w4.w;
    }
    float* vd = v + (m * BATCH + b) * DIM + 4 * tid;
    atomicAdd(vd + 0, acc.x);
    atomicAdd(vd + 1, acc.y);
    atomicAdd(vd + 2, acc.z);
    atomicAdd(vd + 3, acc.w);
}

// y[m,b,e] += sum_{d in chunk} v[m,b,d] * c_proj_w[m,d,e]
__global__ void __launch_bounds__(256) proj_split_kernel(const float* __restrict__ v,
                                                         const float* __restrict__ c_proj_w,
                                                         float* __restrict__ y) {
    int bid = blockIdx.x;            // 256 = m(2) * b(8) * chunk(16)
    int m = bid >> 7;
    int b = (bid >> 4) & 7;
    int c = bid & 15;
    int tid = threadIdx.x;           // owns e = 4*tid .. 4*tid+3
    const float* vr = v + (m * BATCH + b) * DIM + c * ECHUNK;
    const float* w = c_proj_w + (size_t)m * DIM * DIM
                   + (size_t)(c * ECHUNK) * DIM + 4 * tid;
    float4 acc = make_float4(0.f, 0.f, 0.f, 0.f);
#pragma unroll 16
    for (int d = 0; d < ECHUNK; ++d) {
        float vd = vr[d];
        float4 w4 = *reinterpret_cast<const float4*>(w + (size_t)d * DIM);
        acc.x += vd * w4.x; acc.y += vd * w4.y; acc.z += vd * w4.z; acc.w += vd * w4.w;
    }
    float* yd = y + (m * BATCH + b) * DIM + 4 * tid;
    atomicAdd(yd + 0, acc.x);
    atomicAdd(yd + 1, acc.y);
    atomicAdd(yd + 2, acc.z);
    atomicAdd(yd + 3, acc.w);
}

// out[b,q,e] = y[0,b,e] + (b==0 ? y[1,0,e] : 0), broadcast over q
__global__ void __launch_bounds__(256) bcast_kernel(const float* __restrict__ y,
                                                    float* __restrict__ out) {
    const int total4 = BATCH * QLEN * (DIM / 4);   // 8,388,608 float4 stores
    const float4* y4 = reinterpret_cast<const float4*>(y);
    float4* o4 = reinterpret_cast<float4*>(out);
    int stride = gridDim.x * blockDim.x;
    for (int i = blockIdx.x * blockDim.x + threadIdx.x; i < total4; i += stride) {
        int e4 = i & (DIM / 4 - 1);
        int bq = i >> 8;
        int b = bq >> 12;
        float4 val = y4[b * (DIM / 4) + e4];            // y[0,b,:]
        if (b == 0) {
            float4 y1 = y4[BATCH * (DIM / 4) + e4];     // y[1,0,:]
            val.x += y1.x; val.y += y1.y; val.z += y1.z; val.w += y1.w;
        }
        o4[i] = val;
    }
}

extern "C" void kernel_launch(void* const* d_in, const int* in_sizes, int n_in,
                              void* d_out, int out_size, void* d_ws, size_t ws_size,
                              hipStream_t stream) {
    // inputs: encoder_hidden_states, hidden_states, q_w, q_b,
    //         c_attn_w, c_attn_b, c_proj_w, c_proj_b
    const float* hidden   = (const float*)d_in[1];
    const float* c_attn_w = (const float*)d_in[4];
    const float* c_attn_b = (const float*)d_in[5];
    const float* c_proj_w = (const float*)d_in[6];
    const float* c_proj_b = (const float*)d_in[7];
    float* out = (float*)d_out;

    float* v = (float*)d_ws;                    // 16384 f32 = 64 KB
    float* y = v + NMULT * BATCH * DIM;         // 16384 f32 = 64 KB

    init_kernel<<<128, 256, 0, stream>>>(c_attn_b, c_proj_b, v, y);
    kv_split_kernel<<<NMULT * BATCH * ESPLIT, 256, 0, stream>>>(hidden, c_attn_w, v);
    proj_split_kernel<<<NMULT * BATCH * ESPLIT, 256, 0, stream>>>(v, c_proj_w, y);
    bcast_kernel<<<2048, 256, 0, stream>>>(y, out);
}

// Round 4
// 43.783 us; speedup vs baseline: 2.9137x; 1.0855x over previous
//
#include <hip/hip_runtime.h>

#define DIM    1024
#define BATCH  8
#define QLEN   4096
#define SEQ    128
#define NMULT  2
#define ESPLIT 16
#define DCHUNK (DIM / ESPLIT)   // 64

typedef float vfloat4 __attribute__((ext_vector_type(4)));

// One block per (m, b, c): compute v[dchunk] = bias + h·Wv[:,chunk], then
// partial y: yp[m][b][c][e] = sum_{d in chunk} v[d] * Wp[d, e].
__global__ void __launch_bounds__(256) fused_gemv(const float* __restrict__ hidden,
                                                  const float* __restrict__ c_attn_w,
                                                  const float* __restrict__ c_attn_b,
                                                  const float* __restrict__ c_proj_w,
                                                  float* __restrict__ yp) {
    __shared__ float h_lds[DIM];
    __shared__ float vred[4][DCHUNK];
    __shared__ float v_lds[DCHUNK];

    int m = blockIdx.x >> 7;
    int b = (blockIdx.x >> 4) & 7;
    int c = blockIdx.x & 15;
    int tid = threadIdx.x;

    // stage h_last[b,:] (4 KB) into LDS
    const vfloat4* h4 = reinterpret_cast<const vfloat4*>(
        hidden + (size_t)b * (SEQ * DIM) + (size_t)(SEQ - 1) * DIM);
    reinterpret_cast<vfloat4*>(h_lds)[tid] = h4[tid];
    __syncthreads();

    // phase 1: v[dl] partials. wave eg handles e ∈ {eg, eg+4, ...}; lane = dl.
    int eg = tid >> 6;          // 0..3 (wave index)
    int dl = tid & 63;
    int dbase = c * DCHUNK;
    const float* wv = c_attn_w + (size_t)m * DIM * (2 * DIM) + DIM + dbase + dl;
    float acc = 0.f;
#pragma unroll 8
    for (int e = eg; e < DIM; e += 4) {
        acc += h_lds[e] * wv[(size_t)e * (2 * DIM)];
    }
    vred[eg][dl] = acc;
    __syncthreads();
    if (tid < DCHUNK) {
        v_lds[tid] = vred[0][tid] + vred[1][tid] + vred[2][tid] + vred[3][tid]
                   + c_attn_b[m * 2 * DIM + DIM + dbase + tid];
    }
    __syncthreads();

    // phase 2: partial y over this d-chunk; thread owns e = 4*tid..4*tid+3
    const float* wp = c_proj_w + (size_t)m * DIM * DIM + (size_t)dbase * DIM + 4 * tid;
    vfloat4 acc2 = {0.f, 0.f, 0.f, 0.f};
#pragma unroll 8
    for (int d = 0; d < DCHUNK; ++d) {
        float vd = v_lds[d];
        vfloat4 w4 = *reinterpret_cast<const vfloat4*>(wp + (size_t)d * DIM);
        acc2 += vd * w4;
    }
    float* dst = yp + (((m * BATCH + b) * ESPLIT) + c) * DIM + 4 * tid;
    *reinterpret_cast<vfloat4*>(dst) = acc2;
}

// 2048 blocks: b = bid>>8, q0 = (bid&255)*16. Reduce 16 partials + bias into
// registers, then stream 16 rows of out with nontemporal stores.
__global__ void __launch_bounds__(256) bcast_reduce(const float* __restrict__ yp,
                                                    const float* __restrict__ c_proj_b,
                                                    float* __restrict__ out) {
    int b = blockIdx.x >> 8;
    int q0 = (blockIdx.x & 255) * 16;
    int t = threadIdx.x;                       // owns e = 4t..4t+3

    const vfloat4* bias0 = reinterpret_cast<const vfloat4*>(c_proj_b);
    vfloat4 val = bias0[t];                    // m=0 bias
    const vfloat4* base0 = reinterpret_cast<const vfloat4*>(
        yp + (size_t)(0 * BATCH + b) * ESPLIT * DIM) + t;
#pragma unroll
    for (int c = 0; c < ESPLIT; ++c) {
        val += base0[c * (DIM / 4)];
    }
    if (b == 0) {
        vfloat4 v1 = bias0[DIM / 4 + t];       // m=1 bias
        const vfloat4* base1 = reinterpret_cast<const vfloat4*>(
            yp + (size_t)(1 * BATCH + 0) * ESPLIT * DIM) + t;
#pragma unroll
        for (int c = 0; c < ESPLIT; ++c) {
            v1 += base1[c * (DIM / 4)];
        }
        val += v1;
    }

    vfloat4* o = reinterpret_cast<vfloat4*>(out)
               + ((size_t)b * QLEN + q0) * (DIM / 4) + t;
#pragma unroll
    for (int q = 0; q < 16; ++q) {
        __builtin_nontemporal_store(val, o + (size_t)q * (DIM / 4));
    }
}

extern "C" void kernel_launch(void* const* d_in, const int* in_sizes, int n_in,
                              void* d_out, int out_size, void* d_ws, size_t ws_size,
                              hipStream_t stream) {
    // inputs: encoder_hidden_states, hidden_states, q_w, q_b,
    //         c_attn_w, c_attn_b, c_proj_w, c_proj_b
    const float* hidden   = (const float*)d_in[1];
    const float* c_attn_w = (const float*)d_in[4];
    const float* c_attn_b = (const float*)d_in[5];
    const float* c_proj_w = (const float*)d_in[6];
    const float* c_proj_b = (const float*)d_in[7];
    float* out = (float*)d_out;

    float* yp = (float*)d_ws;   // NMULT*BATCH*ESPLIT*DIM f32 = 512 KB

    fused_gemv<<<NMULT * BATCH * ESPLIT, 256, 0, stream>>>(hidden, c_attn_w,
                                                           c_attn_b, c_proj_w, yp);
    bcast_reduce<<<2048, 256, 0, stream>>>(yp, c_proj_b, out);
}

// Round 6
// 37.959 us; speedup vs baseline: 3.3607x; 1.1534x over previous
//
#include <hip/hip_runtime.h>

#define DIM    1024
#define BATCH  8
#define QLEN   4096
#define SEQ    128
#define NMULT  2

typedef float vfloat4 __attribute__((ext_vector_type(4)));

// ---------- Kernel A: vp[es][m,b,d] = sum_{e in es-range} h[b,e]*Wv[m,e,DIM+d]
// grid 512 = m(2) x c(16 d-chunks of 64) x es(16 e-ranges of 64); 256 thr.
// Each weight float4 is read ONCE and feeds all 8 batches.
__global__ void __launch_bounds__(256) kernelA(const float* __restrict__ hidden,
                                               const float* __restrict__ c_attn_w,
                                               float* __restrict__ vp) {
    __shared__ float h_s[BATCH][64];
    __shared__ vfloat4 vred[16][16][9];   // [eg][d4][b] (padded vs 8)

    const int tid = threadIdx.x;
    const int es = blockIdx.x & 15;
    const int c  = (blockIdx.x >> 4) & 15;
    const int m  = blockIdx.x >> 8;

    if (tid < 128) {                       // stage h_last[b, es*64 .. +64)
        int b = tid >> 4, e4 = tid & 15;
        const vfloat4* src = reinterpret_cast<const vfloat4*>(
            hidden + (size_t)b * (SEQ * DIM) + (size_t)(SEQ - 1) * DIM + es * 64);
        reinterpret_cast<vfloat4*>(h_s[b])[e4] = src[e4];
    }
    __syncthreads();

    const int d4 = tid & 15;               // float4 of d within chunk
    const int eg = tid >> 4;               // 16 e-groups of 4
    const float* wbase = c_attn_w + (size_t)m * DIM * (2 * DIM) + DIM + c * 64 + d4 * 4;

    vfloat4 acc[BATCH];
#pragma unroll
    for (int b = 0; b < BATCH; ++b) acc[b] = (vfloat4){0.f, 0.f, 0.f, 0.f};

#pragma unroll
    for (int k = 0; k < 4; ++k) {
        int el = eg * 4 + k;               // 0..63
        int e  = es * 64 + el;
        vfloat4 w4 = *reinterpret_cast<const vfloat4*>(wbase + (size_t)e * (2 * DIM));
#pragma unroll
        for (int b = 0; b < BATCH; ++b) acc[b] += h_s[b][el] * w4;
    }
#pragma unroll
    for (int b = 0; b < BATCH; ++b) vred[eg][d4][b] = acc[b];
    __syncthreads();

    if (tid < 128) {                       // reduce 16 e-groups
        int b = tid >> 4, dq = tid & 15;
        vfloat4 s = vred[0][dq][b];
#pragma unroll
        for (int g = 1; g < 16; ++g) s += vred[g][dq][b];
        reinterpret_cast<vfloat4*>(vp)[es * 4096 + (m * BATCH + b) * 256 + c * 16 + dq] = s;
    }
}

// ---------- Kernel B: yp[cd][m,b,e] = sum_{d in cd-chunk} v[m,b,d]*Wp[m,d,e]
// v = c_attn_b[:,DIM:] + sum_es vp.  grid 512 = m(2) x cd(16) x ce(16); 256 thr.
__global__ void __launch_bounds__(256) kernelB(const float* __restrict__ vp,
                                               const float* __restrict__ c_attn_b,
                                               const float* __restrict__ c_proj_w,
                                               float* __restrict__ yp) {
    __shared__ float v_s[BATCH][64];
    __shared__ vfloat4 yred[16][16][9];    // [dg][e4][b] (padded)

    const int tid = threadIdx.x;
    const int ce = blockIdx.x & 15;
    const int cd = (blockIdx.x >> 4) & 15;
    const int m  = blockIdx.x >> 8;

    if (tid < 128) {                       // v_s[b][dl] for this d-chunk
        int b = tid >> 4, d4 = tid & 15;
        vfloat4 s = reinterpret_cast<const vfloat4*>(
            c_attn_b + (size_t)m * 2 * DIM + DIM)[cd * 16 + d4];
        const vfloat4* vp4 = reinterpret_cast<const vfloat4*>(vp);
#pragma unroll
        for (int es = 0; es < 16; ++es) {
            s += vp4[es * 4096 + (m * BATCH + b) * 256 + cd * 16 + d4];
        }
        reinterpret_cast<vfloat4*>(v_s[b])[d4] = s;
    }
    __syncthreads();

    const int e4 = tid & 15;               // float4 of e within 64-e range
    const int dg = tid >> 4;               // 16 d-groups of 4
    const float* wbase = c_proj_w + (size_t)m * DIM * DIM + ce * 64 + e4 * 4;

    vfloat4 acc[BATCH];
#pragma unroll
    for (int b = 0; b < BATCH; ++b) acc[b] = (vfloat4){0.f, 0.f, 0.f, 0.f};

#pragma unroll
    for (int j = 0; j < 4; ++j) {
        int dl = dg * 4 + j;               // 0..63
        int d  = cd * 64 + dl;
        vfloat4 w4 = *reinterpret_cast<const vfloat4*>(wbase + (size_t)d * DIM);
#pragma unroll
        for (int b = 0; b < BATCH; ++b) acc[b] += v_s[b][dl] * w4;
    }
#pragma unroll
    for (int b = 0; b < BATCH; ++b) yred[dg][e4][b] = acc[b];
    __syncthreads();

    if (tid < 128) {                       // reduce 16 d-groups
        int b = tid >> 4, eq = tid & 15;
        vfloat4 s = yred[0][eq][b];
#pragma unroll
        for (int g = 1; g < 16; ++g) s += yred[g][eq][b];
        reinterpret_cast<vfloat4*>(yp)[cd * 4096 + (m * BATCH + b) * 256 + ce * 16 + eq] = s;
    }
}

// ---------- Kernel C: out[b,q,:] = bias0 + sum_cd yp[cd][0,b] (+ m=1 b=0 term)
// 2048 blocks: b = bid>>8, q0 = (bid&255)*16; 16 q-rows per block.
__global__ void __launch_bounds__(256) bcast_reduce(const float* __restrict__ yp,
                                                    const float* __restrict__ c_proj_b,
                                                    float* __restrict__ out) {
    int b = blockIdx.x >> 8;
    int q0 = (blockIdx.x & 255) * 16;
    int t = threadIdx.x;                   // e4 = t (256 float4 = 1024 e)

    const vfloat4* bias4 = reinterpret_cast<const vfloat4*>(c_proj_b);
    const vfloat4* yp4 = reinterpret_cast<const vfloat4*>(yp);
    vfloat4 val = bias4[t];
#pragma unroll
    for (int cd = 0; cd < 16; ++cd) {
        val += yp4[cd * 4096 + b * 256 + t];
    }
    if (b == 0) {
        val += bias4[256 + t];
#pragma unroll
        for (int cd = 0; cd < 16; ++cd) {
            val += yp4[cd * 4096 + BATCH * 256 + t];
        }
    }

    vfloat4* o = reinterpret_cast<vfloat4*>(out) + ((size_t)b * QLEN + q0) * 256 + t;
#pragma unroll
    for (int q = 0; q < 16; ++q) {
        __builtin_nontemporal_store(val, o + (size_t)q * 256);
    }
}

extern "C" void kernel_launch(void* const* d_in, const int* in_sizes, int n_in,
                              void* d_out, int out_size, void* d_ws, size_t ws_size,
                              hipStream_t stream) {
    // inputs: encoder_hidden_states, hidden_states, q_w, q_b,
    //         c_attn_w, c_attn_b, c_proj_w, c_proj_b
    const float* hidden   = (const float*)d_in[1];
    const float* c_attn_w = (const float*)d_in[4];
    const float* c_attn_b = (const float*)d_in[5];
    const float* c_proj_w = (const float*)d_in[6];
    const float* c_proj_b = (const float*)d_in[7];
    float* out = (float*)d_out;

    float* vp = (float*)d_ws;              // 16*16384 f32 = 1 MB
    float* yp = vp + 16 * 16384;           // 16*16384 f32 = 1 MB

    kernelA<<<512, 256, 0, stream>>>(hidden, c_attn_w, vp);
    kernelB<<<512, 256, 0, stream>>>(vp, c_attn_b, c_proj_w, yp);
    bcast_reduce<<<2048, 256, 0, stream>>>(yp, c_proj_b, out);
}